// Round 6
// baseline (363.672 us; speedup 1.0000x reference)
//
#include <hip/hip_runtime.h>

// Otsu binarization: rgb(16,1024,1024,3) -> gray -> global otsu threshold -> {0,1}
//
// R2 lesson: same-cacheline global atomics serialize (~381us) -> none anywhere.
// R5 lesson: grid.sync() ~100us each on MI355X (cross-XCD atomic spin) -> no
//            cooperative fusion. Plain launches cost only ~8us each.
// R6 lesson: fills (2 x ~120us = 241us) are fixed harness overhead.
// R9/R10 lesson: last-block-done fusion (per-block device-scope
//            release/acquire -> 512 buffer_wbl2/buffer_inv) cost ~47us.
//            NEVER use device-scope fences in bulk-block kernels here.
//            NT hints: neutral (within noise). Baseline re-anchored 356.9.
// R11/R12: kernel boundaries give device coherence for FREE -> fold otsu
//            into k_bin's prelude, computed REDUNDANTLY per block (512 blocks,
//            bit-identical deterministic result, zero communication). 4->3
//            kernels, 3->2 gaps, no whole-GPU-idle 1-block launch. Redundant
//            hist_part reads = 512 x 512KB = 256MiB of L2/L3 hits (~7us,
//            parallel across blocks). (R12 = resubmit; R5-of-session was an
//            infra failure, not a kernel result.)
//
// FP discipline (absmax=0 verified repeatedly): __f*_rn everywhere, einsum
// L-to-R order, true division for bin index, sequential cumsums on one thread.
// One flipped pixel fails absmax, so no FMA/rcp tricks. Integer bin sums are
// order-independent -> per-block redundant reduce stays bit-exact.

static constexpr float W0 = 0.2989f;
static constexpr float W1 = 0.5870f;
static constexpr float W2 = 0.1140f;

static constexpr int GRAY_BLOCKS = 4096;   // 1024 pixel-groups (4096 px) each
static constexpr int HIST_BLOCKS = 512;    // partials: 512*256*4B = 512 KB (L2)
static constexpr int BIN_BLOCKS  = 512;    // 8192 float4 groups per block

__device__ __forceinline__ float gray_of(float r, float g, float b) {
    // einsum 'bhwc,c->bhw': ((r*w0) + (g*w1)) + (b*w2), rn each step, no fma
    return __fadd_rn(__fadd_rn(__fmul_rn(r, W0), __fmul_rn(g, W1)), __fmul_rn(b, W2));
}

__device__ __forceinline__ void wave_minmax(float& lmin, float& lmax) {
    #pragma unroll
    for (int off = 32; off > 0; off >>= 1) {
        lmin = fminf(lmin, __shfl_down(lmin, off));
        lmax = fmaxf(lmax, __shfl_down(lmax, off));
    }
}

// Block-wide reduce of the k_gray min/max partials (L2-resident, 32 KB).
// Deterministic: every calling block computes the same bit pattern.
__device__ __forceinline__ void reduce_partials(
        const float* __restrict__ pmin, const float* __restrict__ pmax,
        int n, int nthreads, float& out_mn, float& out_mx) {
    __shared__ float smin[16], smax[16];
    int t = threadIdx.x;
    float lmin = __uint_as_float(0x7f800000u);   // +inf
    float lmax = -lmin;
    for (int i = t; i < n; i += nthreads) {
        lmin = fminf(lmin, pmin[i]);
        lmax = fmaxf(lmax, pmax[i]);
    }
    wave_minmax(lmin, lmax);
    int nw = nthreads >> 6;
    if ((t & 63) == 0) { smin[t >> 6] = lmin; smax[t >> 6] = lmax; }
    __syncthreads();
    float m = smin[0], M = smax[0];
    for (int w = 1; w < nw; ++w) { m = fminf(m, smin[w]); M = fmaxf(M, smax[w]); }
    out_mn = m; out_mx = M;
    __syncthreads();   // smin/smax reusable by caller
}

// ---- K1: gray + per-block min/max partials. Direct loads, no LDS/barriers.
// Thread handles 4 pixel-groups (16 px, 12 float4 loads in flight). Within a
// wave the 3 stride-48B loads of a group cover a contiguous 3KB span -> L1
// line reuse, no HBM over-fetch.
__global__ __launch_bounds__(256) void k_gray(
        const float4* __restrict__ in4, float4* __restrict__ gray4,
        float* __restrict__ pmin, float* __restrict__ pmax) {
    int t = threadIdx.x;
    int base = blockIdx.x * 1024;              // 1024 groups per block
    float lmin = __uint_as_float(0x7f800000u);
    float lmax = -lmin;
    #pragma unroll
    for (int j = 0; j < 4; ++j) {
        int g = base + j * 256 + t;
        const float4* src = in4 + 3 * (size_t)g;
        float4 a = src[0];
        float4 b = src[1];
        float4 c = src[2];
        float g0 = gray_of(a.x, a.y, a.z);
        float g1 = gray_of(a.w, b.x, b.y);
        float g2 = gray_of(b.z, b.w, c.x);
        float g3 = gray_of(c.y, c.z, c.w);
        float4 o; o.x = g0; o.y = g1; o.z = g2; o.w = g3;
        gray4[g] = o;
        lmin = fminf(lmin, fminf(fminf(g0, g1), fminf(g2, g3)));
        lmax = fmaxf(lmax, fmaxf(fmaxf(g0, g1), fmaxf(g2, g3)));
    }
    wave_minmax(lmin, lmax);
    __shared__ float smin[4], smax[4];
    if ((t & 63) == 0) { smin[t >> 6] = lmin; smax[t >> 6] = lmax; }
    __syncthreads();
    if (t == 0) {
        pmin[blockIdx.x] = fminf(fminf(smin[0], smin[1]), fminf(smin[2], smin[3]));
        pmax[blockIdx.x] = fmaxf(fmaxf(smax[0], smax[1]), fmaxf(smax[2], smax[3]));
    }
}

// ---- K2: inline minmax reduce + per-wave LDS hists -> per-block partial ----
__global__ __launch_bounds__(256) void k_hist(
        const float4* __restrict__ gray4,
        const float* __restrict__ pmin, const float* __restrict__ pmax,
        unsigned* __restrict__ hist_part, int npix4) {
    float mn, mx;
    reduce_partials(pmin, pmax, GRAY_BLOCKS, 256, mn, mx);
    float width = __fdiv_rn(__fsub_rn(mx, mn), 256.0f);

    __shared__ unsigned lh[1024];      // one 256-bin hist per wave
    for (int j = threadIdx.x; j < 1024; j += 256) lh[j] = 0u;
    __syncthreads();
    unsigned* myh = &lh[(threadIdx.x >> 6) << 8];
    int stride = gridDim.x * 256;
    for (int i = blockIdx.x * 256 + threadIdx.x; i < npix4; i += stride) {
        float4 g = gray4[i];
        // reference: int32((x - mn) / width) clipped to [0,255] — true division
        int i0 = (int)__fdiv_rn(__fsub_rn(g.x, mn), width);
        int i1 = (int)__fdiv_rn(__fsub_rn(g.y, mn), width);
        int i2 = (int)__fdiv_rn(__fsub_rn(g.z, mn), width);
        int i3 = (int)__fdiv_rn(__fsub_rn(g.w, mn), width);
        i0 = min(max(i0, 0), 255);
        i1 = min(max(i1, 0), 255);
        i2 = min(max(i2, 0), 255);
        i3 = min(max(i3, 0), 255);
        atomicAdd(&myh[i0], 1u);       // LDS atomics only
        atomicAdd(&myh[i1], 1u);
        atomicAdd(&myh[i2], 1u);
        atomicAdd(&myh[i3], 1u);
    }
    __syncthreads();
    int b = threadIdx.x;               // one bin per thread, coalesced store
    hist_part[(size_t)blockIdx.x * 256 + b] =
        lh[b] + lh[256 + b] + lh[512 + b] + lh[768 + b];
}

// ---- K3: per-block redundant Otsu prelude (bit-identical on every block;
// hist_part/pmin/pmax are read-only here -> no fences, kernel boundary gives
// coherence), then pure stream binarize. ----
__global__ __launch_bounds__(256) void k_bin_otsu(
        float4* __restrict__ g4, const unsigned* __restrict__ hist_part,
        const float* __restrict__ pmin, const float* __restrict__ pmax) {
    float mn, mx;
    reduce_partials(pmin, pmax, GRAY_BLOCKS, 256, mn, mx);
    float width = __fdiv_rn(__fsub_rn(mx, mn), 256.0f);

    __shared__ float counts[256], centers[256], tt[256];
    __shared__ float w1[256], s1[256], w2[256], s2[256], vv[256];
    __shared__ float sth;
    int b = threadIdx.x;
    unsigned acc = 0;
    #pragma unroll 8
    for (int k = 0; k < HIST_BLOCKS; ++k)      // coalesced: thread b -> k*256+b
        acc += hist_part[(size_t)k * 256 + b]; // L2/L3 hits (512 KB, hot)
    counts[b] = (float)acc;                    // exact: counts <= 2^24
    centers[b] = __fadd_rn(mn, __fmul_rn(width, __fadd_rn((float)b, 0.5f)));
    tt[b] = __fmul_rn(counts[b], centers[b]);
    __syncthreads();
    if (b == 0) {
        float aw = 0.0f, as = 0.0f;
        #pragma unroll 16
        for (int i = 0; i < 256; ++i) {        // forward cumsum (np order)
            aw = __fadd_rn(aw, counts[i]); w1[i] = aw;
            as = __fadd_rn(as, tt[i]);     s1[i] = as;
        }
        aw = 0.0f; as = 0.0f;
        #pragma unroll 16
        for (int i = 255; i >= 0; --i) {       // reversed cumsum
            aw = __fadd_rn(aw, counts[i]); w2[i] = aw;
            as = __fadd_rn(as, tt[i]);     s2[i] = as;
        }
    }
    __syncthreads();
    if (b < 255) {
        float m1 = __fdiv_rn(s1[b],     fmaxf(w1[b],     1.0f));
        float m2 = __fdiv_rn(s2[b + 1], fmaxf(w2[b + 1], 1.0f));
        float d  = __fsub_rn(m1, m2);
        // python eval order: (w1*w2) * (d**2)
        vv[b] = __fmul_rn(__fmul_rn(w1[b], w2[b + 1]), __fmul_rn(d, d));
    }
    __syncthreads();
    if (b == 0) {
        float best = -1.0f; int bi = 0;
        #pragma unroll 16
        for (int i = 0; i < 255; ++i) {        // strict > == first argmax
            float v = vv[i];
            if (v > best) { best = v; bi = i; }
        }
        sth = centers[bi];
    }
    __syncthreads();
    const float th = sth;

    // stream binarize: 8192 contiguous float4 groups per block, 32 iters
    int base = blockIdx.x * 8192;
    #pragma unroll 4
    for (int j = 0; j < 32; ++j) {
        int i = base + j * 256 + b;
        float4 g = g4[i];
        float4 o;
        o.x = g.x > th ? 1.0f : 0.0f;
        o.y = g.y > th ? 1.0f : 0.0f;
        o.z = g.z > th ? 1.0f : 0.0f;
        o.w = g.w > th ? 1.0f : 0.0f;
        g4[i] = o;
    }
}

extern "C" void kernel_launch(void* const* d_in, const int* in_sizes, int n_in,
                              void* d_out, int out_size, void* d_ws, size_t ws_size,
                              hipStream_t stream) {
    const float4* in4 = (const float4*)d_in[0];
    float4* gray4 = (float4*)d_out;          // d_out doubles as the gray buffer

    int npix = in_sizes[0] / 3;              // 16*1024*1024
    int npix4 = npix / 4;                    // 4,194,304 float4 groups

    // ws layout (all 4B-aligned):
    float* pmin = (float*)d_ws;                             // GRAY_BLOCKS
    float* pmax = pmin + GRAY_BLOCKS;                       // GRAY_BLOCKS
    unsigned* hist_part = (unsigned*)(pmax + GRAY_BLOCKS);  // HIST_BLOCKS*256

    k_gray<<<GRAY_BLOCKS, 256, 0, stream>>>(in4, gray4, pmin, pmax);
    k_hist<<<HIST_BLOCKS, 256, 0, stream>>>((const float4*)d_out, pmin, pmax,
                                            hist_part, npix4);
    k_bin_otsu<<<BIN_BLOCKS, 256, 0, stream>>>(gray4, hist_part, pmin, pmax);
}

// Round 7
// 356.636 us; speedup vs baseline: 1.0197x; 1.0197x over previous
//
#include <hip/hip_runtime.h>

// Otsu binarization: rgb(16,1024,1024,3) -> gray -> global otsu threshold -> {0,1}
//
// R2 lesson: same-cacheline global atomics serialize (~381us) -> none anywhere.
// R5 lesson: grid.sync() ~100us each on MI355X (cross-XCD atomic spin) -> no
//            cooperative fusion. Plain launches cost only ~8us each.
// R6 lesson: fills (2 x ~120us = 241us) are fixed harness overhead.
// R9/R10 lesson: last-block-done fusion (per-block device-scope
//            release/acquire -> 512 buffer_wbl2/buffer_inv) cost ~47us.
//            NEVER device-scope fences in bulk-block kernels here.
// R11/R12 lesson: 3-launch redundant-otsu-prelude in k_bin cost +6.8us vs
//            anchor: 512 blocks x 512KB concurrent hist_part reads (~8us
//            through per-XCD L2) + ~3us serial prelude > the ~13us saved
//            from dropping one gap + k_otsu. Structure retired.
// R13 (this): revert to the exact 4-launch anchor (356.9us verified R4/prior
//            session 357.8). Every cross-block-sharing alternative measured
//            worse; kernel launches are the cheapest synchronization on MI355X.
//
// FP discipline (absmax=0 verified repeatedly): __f*_rn everywhere, einsum
// L-to-R order, true division for bin index, sequential cumsums on one thread.
// One flipped pixel fails absmax, so no FMA/rcp tricks.

static constexpr float W0 = 0.2989f;
static constexpr float W1 = 0.5870f;
static constexpr float W2 = 0.1140f;

static constexpr int GRAY_BLOCKS = 4096;   // 1024 pixel-groups (4096 px) each
static constexpr int HIST_BLOCKS = 512;    // partials: 512*256*4B = 512 KB (L2)
static constexpr int BIN_BLOCKS  = 4096;   // flat, 4 float4 per thread

__device__ __forceinline__ float gray_of(float r, float g, float b) {
    // einsum 'bhwc,c->bhw': ((r*w0) + (g*w1)) + (b*w2), rn each step, no fma
    return __fadd_rn(__fadd_rn(__fmul_rn(r, W0), __fmul_rn(g, W1)), __fmul_rn(b, W2));
}

__device__ __forceinline__ void wave_minmax(float& lmin, float& lmax) {
    #pragma unroll
    for (int off = 32; off > 0; off >>= 1) {
        lmin = fminf(lmin, __shfl_down(lmin, off));
        lmax = fmaxf(lmax, __shfl_down(lmax, off));
    }
}

// Block-wide reduce of the k_gray min/max partials (L2-resident, 32 KB).
// Deterministic: every calling block computes the same bit pattern.
__device__ __forceinline__ void reduce_partials(
        const float* __restrict__ pmin, const float* __restrict__ pmax,
        int n, int nthreads, float& out_mn, float& out_mx) {
    __shared__ float smin[16], smax[16];
    int t = threadIdx.x;
    float lmin = __uint_as_float(0x7f800000u);   // +inf
    float lmax = -lmin;
    for (int i = t; i < n; i += nthreads) {
        lmin = fminf(lmin, pmin[i]);
        lmax = fmaxf(lmax, pmax[i]);
    }
    wave_minmax(lmin, lmax);
    int nw = nthreads >> 6;
    if ((t & 63) == 0) { smin[t >> 6] = lmin; smax[t >> 6] = lmax; }
    __syncthreads();
    float m = smin[0], M = smax[0];
    for (int w = 1; w < nw; ++w) { m = fminf(m, smin[w]); M = fmaxf(M, smax[w]); }
    out_mn = m; out_mx = M;
    __syncthreads();   // smin/smax reusable by caller
}

// ---- K1: gray + per-block min/max partials. Direct loads, no LDS/barriers.
// Thread handles 4 pixel-groups (16 px, 12 float4 loads in flight). Within a
// wave the 3 stride-48B loads of a group cover a contiguous 3KB span -> L1
// line reuse, no HBM over-fetch.
__global__ __launch_bounds__(256) void k_gray(
        const float4* __restrict__ in4, float4* __restrict__ gray4,
        float* __restrict__ pmin, float* __restrict__ pmax) {
    int t = threadIdx.x;
    int base = blockIdx.x * 1024;              // 1024 groups per block
    float lmin = __uint_as_float(0x7f800000u);
    float lmax = -lmin;
    #pragma unroll
    for (int j = 0; j < 4; ++j) {
        int g = base + j * 256 + t;
        const float4* src = in4 + 3 * (size_t)g;
        float4 a = src[0];
        float4 b = src[1];
        float4 c = src[2];
        float g0 = gray_of(a.x, a.y, a.z);
        float g1 = gray_of(a.w, b.x, b.y);
        float g2 = gray_of(b.z, b.w, c.x);
        float g3 = gray_of(c.y, c.z, c.w);
        float4 o; o.x = g0; o.y = g1; o.z = g2; o.w = g3;
        gray4[g] = o;
        lmin = fminf(lmin, fminf(fminf(g0, g1), fminf(g2, g3)));
        lmax = fmaxf(lmax, fmaxf(fmaxf(g0, g1), fmaxf(g2, g3)));
    }
    wave_minmax(lmin, lmax);
    __shared__ float smin[4], smax[4];
    if ((t & 63) == 0) { smin[t >> 6] = lmin; smax[t >> 6] = lmax; }
    __syncthreads();
    if (t == 0) {
        pmin[blockIdx.x] = fminf(fminf(smin[0], smin[1]), fminf(smin[2], smin[3]));
        pmax[blockIdx.x] = fmaxf(fmaxf(smax[0], smax[1]), fmaxf(smax[2], smax[3]));
    }
}

// ---- K2: inline minmax reduce + per-wave LDS hists -> per-block partial ----
__global__ __launch_bounds__(256) void k_hist(
        const float4* __restrict__ gray4,
        const float* __restrict__ pmin, const float* __restrict__ pmax,
        unsigned* __restrict__ hist_part, int npix4) {
    float mn, mx;
    reduce_partials(pmin, pmax, GRAY_BLOCKS, 256, mn, mx);
    float width = __fdiv_rn(__fsub_rn(mx, mn), 256.0f);

    __shared__ unsigned lh[1024];      // one 256-bin hist per wave
    for (int j = threadIdx.x; j < 1024; j += 256) lh[j] = 0u;
    __syncthreads();
    unsigned* myh = &lh[(threadIdx.x >> 6) << 8];
    int stride = gridDim.x * 256;
    for (int i = blockIdx.x * 256 + threadIdx.x; i < npix4; i += stride) {
        float4 g = gray4[i];
        // reference: int32((x - mn) / width) clipped to [0,255] — true division
        int i0 = (int)__fdiv_rn(__fsub_rn(g.x, mn), width);
        int i1 = (int)__fdiv_rn(__fsub_rn(g.y, mn), width);
        int i2 = (int)__fdiv_rn(__fsub_rn(g.z, mn), width);
        int i3 = (int)__fdiv_rn(__fsub_rn(g.w, mn), width);
        i0 = min(max(i0, 0), 255);
        i1 = min(max(i1, 0), 255);
        i2 = min(max(i2, 0), 255);
        i3 = min(max(i3, 0), 255);
        atomicAdd(&myh[i0], 1u);       // LDS atomics only
        atomicAdd(&myh[i1], 1u);
        atomicAdd(&myh[i2], 1u);
        atomicAdd(&myh[i3], 1u);
    }
    __syncthreads();
    int b = threadIdx.x;               // one bin per thread, coalesced store
    hist_part[(size_t)blockIdx.x * 256 + b] =
        lh[b] + lh[256 + b] + lh[512 + b] + lh[768 + b];
}

// ---- K3: single block -> final histogram + bit-exact sequential Otsu ----
__global__ __launch_bounds__(1024) void k_otsu(
        const unsigned* __restrict__ hist_part,
        const float* __restrict__ pmin, const float* __restrict__ pmax,
        float* __restrict__ thresh) {
    float mn, mx;
    reduce_partials(pmin, pmax, GRAY_BLOCKS, 1024, mn, mx);
    float width = __fdiv_rn(__fsub_rn(mx, mn), 256.0f);

    __shared__ unsigned csum[1024];
    __shared__ float counts[256], centers[256], tt[256];
    __shared__ float w1[256], s1[256], w2[256], s2[256], vv[256];
    int t = threadIdx.x;
    int b = t & 255, q = t >> 8;
    unsigned acc = 0;
    #pragma unroll 8
    for (int k = q; k < HIST_BLOCKS; k += 4)   // coalesced: thread b -> k*256+b
        acc += hist_part[(size_t)k * 256 + b];
    csum[q * 256 + b] = acc;
    __syncthreads();
    if (t < 256) {
        unsigned c = csum[t] + csum[256 + t] + csum[512 + t] + csum[768 + t];
        counts[t] = (float)c;                  // exact: counts <= 2^24
        centers[t] = __fadd_rn(mn, __fmul_rn(width, __fadd_rn((float)t, 0.5f)));
        tt[t] = __fmul_rn(counts[t], centers[t]);
    }
    __syncthreads();
    if (t == 0) {
        float aw = 0.0f, as = 0.0f;
        #pragma unroll 16
        for (int i = 0; i < 256; ++i) {        // forward cumsum (np order)
            aw = __fadd_rn(aw, counts[i]); w1[i] = aw;
            as = __fadd_rn(as, tt[i]);     s1[i] = as;
        }
        aw = 0.0f; as = 0.0f;
        #pragma unroll 16
        for (int i = 255; i >= 0; --i) {       // reversed cumsum
            aw = __fadd_rn(aw, counts[i]); w2[i] = aw;
            as = __fadd_rn(as, tt[i]);     s2[i] = as;
        }
    }
    __syncthreads();
    if (t < 255) {
        float m1 = __fdiv_rn(s1[t],     fmaxf(w1[t],     1.0f));
        float m2 = __fdiv_rn(s2[t + 1], fmaxf(w2[t + 1], 1.0f));
        float d  = __fsub_rn(m1, m2);
        // python eval order: (w1*w2) * (d**2)
        vv[t] = __fmul_rn(__fmul_rn(w1[t], w2[t + 1]), __fmul_rn(d, d));
    }
    __syncthreads();
    if (t == 0) {
        float best = -1.0f; int bi = 0;
        #pragma unroll 16
        for (int i = 0; i < 255; ++i) {        // strict > == first argmax
            float v = vv[i];
            if (v > best) { best = v; bi = i; }
        }
        *thresh = centers[bi];
    }
}

// ---- K4: pure stream binarize, threshold via 1-float broadcast load ----
__global__ __launch_bounds__(256) void k_bin(
        float4* __restrict__ g4, const float* __restrict__ thresh) {
    const float th = thresh[0];
    int t = threadIdx.x;
    int base = blockIdx.x * 1024;
    #pragma unroll
    for (int j = 0; j < 4; ++j) {
        int i = base + j * 256 + t;
        float4 g = g4[i];
        float4 o;
        o.x = g.x > th ? 1.0f : 0.0f;
        o.y = g.y > th ? 1.0f : 0.0f;
        o.z = g.z > th ? 1.0f : 0.0f;
        o.w = g.w > th ? 1.0f : 0.0f;
        g4[i] = o;
    }
}

extern "C" void kernel_launch(void* const* d_in, const int* in_sizes, int n_in,
                              void* d_out, int out_size, void* d_ws, size_t ws_size,
                              hipStream_t stream) {
    const float4* in4 = (const float4*)d_in[0];
    float4* gray4 = (float4*)d_out;          // d_out doubles as the gray buffer

    int npix = in_sizes[0] / 3;              // 16*1024*1024
    int npix4 = npix / 4;                    // 4,194,304 float4 groups

    // ws layout (all 4B-aligned):
    float* pmin = (float*)d_ws;                             // GRAY_BLOCKS
    float* pmax = pmin + GRAY_BLOCKS;                       // GRAY_BLOCKS
    float* thresh = pmax + GRAY_BLOCKS;                     // 1
    unsigned* hist_part = (unsigned*)(thresh + 1);          // HIST_BLOCKS*256

    k_gray<<<GRAY_BLOCKS, 256, 0, stream>>>(in4, gray4, pmin, pmax);
    k_hist<<<HIST_BLOCKS, 256, 0, stream>>>((const float4*)d_out, pmin, pmax,
                                            hist_part, npix4);
    k_otsu<<<1, 1024, 0, stream>>>(hist_part, pmin, pmax, thresh);
    k_bin<<<BIN_BLOCKS, 256, 0, stream>>>(gray4, thresh);
}